// Round 12
// baseline (131.560 us; speedup 1.0000x reference)
//
#include <hip/hip_runtime.h>

#define Bv 256
#define Tv 200
#define Cv 40
#define H1v 512
#define H2v 256
#define Ov 12
#define THv 1.0f
#define NT 13        // 13 tiles of 16 timesteps (padded to 208)
#define TPAD 208
#define RW 36        // u32 words per padded x row (72 f16; 40 data + 32 zero)

typedef unsigned long long u64;
typedef _Float16 half8 __attribute__((ext_vector_type(8)));
typedef float    f32x4 __attribute__((ext_vector_type(4)));
typedef _Float16 f16x2 __attribute__((ext_vector_type(2)));
typedef __fp16   g16x2 __attribute__((ext_vector_type(2)));

#if defined(__has_builtin)
#if __has_builtin(__builtin_amdgcn_fdot2)
#define HAVE_FDOT2 1
#endif
#endif

static __device__ __forceinline__ unsigned pkrtz(float a, float b) {
    union { g16x2 h; unsigned u; } cv;
    cv.h = __builtin_amdgcn_cvt_pkrtz(a, b);
    return cv.u;
}
static __device__ __forceinline__ float dot2acc(unsigned a, unsigned b, float c) {
#ifdef HAVE_FDOT2
    union { unsigned u; f16x2 h; } A, B; A.u = a; B.u = b;
    return __builtin_amdgcn_fdot2(A.h, B.h, c, false);
#else
    union { unsigned u; f16x2 h; } A, B; A.u = a; B.u = b;
    return c + (float)A.h.x * (float)B.h.x + (float)A.h.y * (float)B.h.y;
#endif
}
static __device__ __forceinline__ half8 toh8(uint4 q) {
    union { uint4 u; half8 h; } cv; cv.u = q; return cv.h;
}
static __device__ __forceinline__ float lo2f(unsigned u) {
    union { unsigned u; f16x2 h; } cv; cv.u = u; return (float)cv.h.x;
}
static __device__ __forceinline__ float hi2f(unsigned u) {
    union { unsigned u; f16x2 h; } cv; cv.u = u; return (float)cv.h.y;
}

// ---------------------------------------------------------------------------
// One block per batch element, 512 threads (8 waves).
//
// PHASE 1 (speculative): MFMA GEMM I1 = X[200,40]·W1^T (13 tiles of
// mfma_f32_16x16x32_f16, layout HW-verified by R11's in-kernel self-check)
// + in-register EMA scan. R12 changes vs R11 (post-mortem: scan epilogue
// VALU + staging were ~2/3 of the 24us):
//  (a) vmax via sound per-group upper bound al*relu(v_start)+kk*max_j(q_j)
//      from the Horner intermediates already computed for the compose
//      constant (slack <= (al-al^4)|v| ~ 0.03, far from the 0.9 margin) —
//      deletes the 16-step serial inner loop;
//  (b) staging reads x as contiguous float4 (4 sweeps), pad zeroed by two
//      dedicated uint4 loops; self-check W1 loads as float4;
//  (c) explicit next-tile A-frag prefetch.
//
// Layout armor: every lane self-checks its tile-0 quad of MFMA outputs
// against direct dot2 on the same f16 data; mismatch -> bad -> PHASE 2.
//
// Gate soundness for ANY input: err = 40*xmax*wmax*2^-8 (f16 inputs, fp32
// accum) + dmax*2^-10 (f16-packed c compose, geometric sum) + 1e-4 (fp32
// assoc). EMA convex => |v_hat-v|<=err. Fast path iff err<0.25 &&
// vmax_ub<1-err && selfcheck ok; NaN/Inf fail -> exact.
// PHASE 2 = verbatim R1 harness-verified fp32 kernel (x restaged fp32).
// ---------------------------------------------------------------------------
__global__ __launch_bounds__(512) void snn_main(
    const float* __restrict__ x,
    const float* __restrict__ W1,
    const float* __restrict__ Wrec,
    const float* __restrict__ W2,
    const float* __restrict__ Wout,
    const float* __restrict__ alpha1, const float* __restrict__ rho1, const float* __restrict__ ba1,
    const float* __restrict__ alpha2, const float* __restrict__ rho2, const float* __restrict__ ba2,
    const float* __restrict__ beta_out,
    float* __restrict__ out)
{
    // union: phase 1 = packed-f16 x [208][36 u32] (29952 B); phase 2 = fp32 x (32000 B)
    __shared__ __align__(16) unsigned char lds_u[Tv * Cv * 4];
    __shared__ __align__(16) u64 s_m1[2][8];
    __shared__ __align__(16) u64 s_m2[2][4];
    __shared__ __align__(16) u64 s_red[8];
    __shared__ float s_xmax[8], s_wmax[8], s_dmax[8];

    unsigned* lds_xh = (unsigned*)lds_u;
    float*    lds_x  = (float*)lds_u;

    const int b    = blockIdx.x;
    const int tid  = threadIdx.x;
    const int lane = tid & 63;
    const int wid  = tid >> 6;
    const int g    = lane >> 4;       // 4-row group within wave
    const int cl   = lane & 15;       // column-within-subtile

    const float* __restrict__ xg = x + (size_t)b * (Tv * Cv);

    // --- zero the pad region of lds_xh (uint4 stores) ---
    {
        const uint4 z = make_uint4(0u, 0u, 0u, 0u);
        // rows 0..199, words 20..35  (4 uint4 per row)
        for (int i = tid; i < 800; i += 512) {
            const int r = i >> 2, h = i & 3;
            *(uint4*)(lds_xh + r * RW + 20 + 4 * h) = z;
        }
        // rows 200..207, full 36 words = 72 uint4 starting at word 7200
        for (int i = tid; i < 72; i += 512)
            *(uint4*)(lds_xh + 7200 + 4 * i) = z;
    }

    // --- stage x data words as packed f16 (contiguous float4 reads); max|x| ---
    float xm = 0.f;
    {
        const float4* xg4 = (const float4*)xg;          // 2000 contiguous float4
        for (int i = tid; i < 2000; i += 512) {
            const float4 v = xg4[i];
            const int r = i / 10, c = i - r * 10;       // row, quad-within-row
            xm = fmaxf(xm, fmaxf(fmaxf(fabsf(v.x), fabsf(v.y)),
                                 fmaxf(fabsf(v.z), fabsf(v.w))));
            uint2 pk;
            pk.x = pkrtz(v.x, v.y);
            pk.y = pkrtz(v.z, v.w);
            *(uint2*)(lds_xh + r * RW + 2 * c) = pk;
        }
    }

    // --- W1 slice -> f16 B-fragments in registers (4 subtiles x 2 K-halves) ---
    uint4 bfr[4][2];
    float wm = 0.f;
    #pragma unroll
    for (int s = 0; s < 4; ++s) {
        const int h = (wid << 6) + (s << 4) + cl;
        {   // K-half 0: k = g*8 .. g*8+7 (all < 40)
            const float4 q0 = *(const float4*)(W1 + h * Cv + g * 8);
            const float4 q1 = *(const float4*)(W1 + h * Cv + g * 8 + 4);
            wm = fmaxf(wm, fmaxf(fmaxf(fabsf(q0.x), fabsf(q0.y)), fmaxf(fabsf(q0.z), fabsf(q0.w))));
            wm = fmaxf(wm, fmaxf(fmaxf(fabsf(q1.x), fabsf(q1.y)), fmaxf(fabsf(q1.z), fabsf(q1.w))));
            bfr[s][0] = make_uint4(pkrtz(q0.x, q0.y), pkrtz(q0.z, q0.w),
                                   pkrtz(q1.x, q1.y), pkrtz(q1.z, q1.w));
        }
        if (g == 0) {  // K-half 1: k = 32..39 valid only for group 0; others zero
            const float4 q2 = *(const float4*)(W1 + h * Cv + 32);
            const float4 q3 = *(const float4*)(W1 + h * Cv + 36);
            wm = fmaxf(wm, fmaxf(fmaxf(fabsf(q2.x), fabsf(q2.y)), fmaxf(fabsf(q2.z), fabsf(q2.w))));
            wm = fmaxf(wm, fmaxf(fmaxf(fabsf(q3.x), fabsf(q3.y)), fmaxf(fabsf(q3.z), fabsf(q3.w))));
            bfr[s][1] = make_uint4(pkrtz(q2.x, q2.y), pkrtz(q2.z, q2.w),
                                   pkrtz(q3.x, q3.y), pkrtz(q3.z, q3.w));
        } else {
            bfr[s][1] = make_uint4(0u, 0u, 0u, 0u);
        }
    }

    // reduce xmax / wmax to shared
    #pragma unroll
    for (int o = 32; o > 0; o >>= 1) { xm = fmaxf(xm, __shfl_xor(xm, o)); wm = fmaxf(wm, __shfl_xor(wm, o)); }
    if (lane == 0) { s_xmax[wid] = xm; s_wmax[wid] = wm; }
    __syncthreads();

    // per-lane alphas for its 4 columns
    float al[4], kk[4], al4[4], vc[4];
    #pragma unroll
    for (int s = 0; s < 4; ++s) {
        al[s] = alpha1[(wid << 6) + (s << 4) + cl];
        kk[s] = 1.f - al[s];
        const float a2 = al[s] * al[s];
        al4[s] = a2 * a2;
        vc[s] = 0.f;
    }

    // ================= PHASE 1: MFMA GEMM + in-register EMA scan =============
    bool bad = false;
    float vmax = 0.f, dmax = 0.f;

    // A-fragment pointers: row = it*16+cl, k-halves at word offsets g*4 and 16+g*4
    const unsigned* ap = lds_xh + cl * RW + g * 4;
    uint4 a0 = *(const uint4*)ap;
    uint4 a1 = *(const uint4*)(ap + 16);

    for (int it = 0; it < NT; ++it) {
        // prefetch next tile's A-fragments
        uint4 na0, na1;
        if (it + 1 < NT) {
            const unsigned* np = ap + 16 * RW;
            na0 = *(const uint4*)np;
            na1 = *(const uint4*)(np + 16);
            ap += 16 * RW;
        }

        f32x4 acc[4];
        #pragma unroll
        for (int s = 0; s < 4; ++s) {
            f32x4 c = {0.f, 0.f, 0.f, 0.f};
            c = __builtin_amdgcn_mfma_f32_16x16x32_f16(toh8(a0), toh8(bfr[s][0]), c, 0, 0, 0);
            c = __builtin_amdgcn_mfma_f32_16x16x32_f16(toh8(a1), toh8(bfr[s][1]), c, 0, 0, 0);
            acc[s] = c;
        }

        // ---- one-time layout self-check: lane's subtile-0 quad vs direct dot2
        if (it == 0) {
            const int h = (wid << 6) + cl;
            unsigned wrow[20];
            #pragma unroll
            for (int m = 0; m < 10; ++m) {
                const float4 q = *(const float4*)(W1 + h * Cv + 4 * m);
                wrow[2*m]   = pkrtz(q.x, q.y);
                wrow[2*m+1] = pkrtz(q.z, q.w);
            }
            #pragma unroll
            for (int j = 0; j < 4; ++j) {
                const int t = g * 4 + j;
                float dd = 0.f;
                #pragma unroll
                for (int m = 0; m < 20; ++m) dd = dot2acc(lds_xh[t * RW + m], wrow[m], dd);
                const float ref = acc[0][j];
                if (!(fabsf(dd - ref) <= 2e-3f + 2e-3f * fabsf(dd))) bad = true;
            }
        }

        // ---- per-subtile: Horner chain -> compose constant + qmax upper bound
        float cS[4], qmx[4];
        #pragma unroll
        for (int s = 0; s < 4; ++s) {
            const float d0 = acc[s][0], d1 = acc[s][1], d2 = acc[s][2], d3 = acc[s][3];
            dmax = fmaxf(dmax, fmaxf(fmaxf(fabsf(d0), fabsf(d1)), fmaxf(fabsf(d2), fabsf(d3))));
            const float q0 = d0;
            const float q1 = al[s] * q0 + d1;
            const float q2 = al[s] * q1 + d2;
            const float q3 = al[s] * q2 + d3;
            cS[s]  = kk[s] * q3;
            qmx[s] = fmaxf(fmaxf(q0, q1), fmaxf(q2, q3));
        }

        // ---- gather compose constants across the 4 row-groups (packed f16)
        const unsigned w01 = pkrtz(cS[0], cS[1]);
        const unsigned w23 = pkrtz(cS[2], cS[3]);
        unsigned cg01[4], cg23[4];
        #pragma unroll
        for (int gp = 0; gp < 4; ++gp) {
            cg01[gp] = (unsigned)__shfl((int)w01, cl + (gp << 4));
            cg23[gp] = (unsigned)__shfl((int)w23, cl + (gp << 4));
        }
        #pragma unroll
        for (int s = 0; s < 4; ++s) {
            float cgv[4];
            #pragma unroll
            for (int gp = 0; gp < 4; ++gp)
                cgv[gp] = (s == 0) ? lo2f(cg01[gp]) : (s == 1) ? hi2f(cg01[gp])
                        : (s == 2) ? lo2f(cg23[gp]) : hi2f(cg23[gp]);
            const float v0s = vc[s];
            const float v1s = al4[s] * v0s + cgv[0];
            const float v2s = al4[s] * v1s + cgv[1];
            const float v3s = al4[s] * v2s + cgv[2];
            vc[s]           = al4[s] * v3s + cgv[3];
            const float vst = (g == 0) ? v0s : (g == 1) ? v1s : (g == 2) ? v2s : v3s;
            // sound upper bound over this lane's 4 rows:
            //   v(g4+j) = al^(j+1) vst + kk q_j <= al*max(vst,0) + kk*qmax
            const float vub = al[s] * fmaxf(vst, 0.f) + kk[s] * qmx[s];
            vmax = fmaxf(vmax, vub);
        }

        a0 = na0; a1 = na1;
    }

    // block maxima + gate
    {
        float dm = dmax;
        #pragma unroll
        for (int o = 32; o > 0; o >>= 1) dm = fmaxf(dm, __shfl_xor(dm, o));
        if (lane == 0) s_dmax[wid] = dm;
    }
    __syncthreads();
    {
        float xmax = s_xmax[0], wmax = s_wmax[0], dmx = s_dmax[0];
        #pragma unroll
        for (int i = 1; i < 8; ++i) {
            xmax = fmaxf(xmax, s_xmax[i]);
            wmax = fmaxf(wmax, s_wmax[i]);
            dmx  = fmaxf(dmx,  s_dmax[i]);
        }
        const float err = 40.f * xmax * wmax * (1.f / 256.f) + dmx * (1.f / 1024.f) + 1e-4f;
        bad = bad || !((err < 0.25f) && (vmax < 1.0f - err));
    }

    {
        const u64 bal = __ballot(bad);
        if (lane == 0) s_red[wid] = bal;
        __syncthreads();
        u64 any = 0ull;
        #pragma unroll
        for (int i = 0; i < 8; ++i) any |= s_red[i];
        if (any == 0ull) {
            // Provably spike-free: every downstream signal is exactly zero.
            if (tid < Ov) out[b * Ov + tid] = 0.f;
            return;
        }
    }

    // ================= PHASE 2: exact coupled simulation (rare) ===============
    // Restage fp32 x (phase-1 f16 reads all completed before the ballot barrier).
    for (int i = tid; i < Tv * Cv; i += 512) lds_x[i] = xg[i];

    float4 w1r[10];
    {
        const float4* p = (const float4*)(W1 + tid * Cv);
        #pragma unroll
        for (int i = 0; i < 10; ++i) w1r[i] = p[i];
    }
    const float al1 = alpha1[tid];
    const float rh1 = rho1[tid], bb1 = ba1[tid];
    float v1 = 0.f, a1p = 0.f, spk1 = 0.f;
    float al2 = 0.f, rh2 = 0.f, bb2 = 0.f, v2 = 0.f, a2 = 0.f;
    if (tid < H2v) { al2 = alpha2[tid]; rh2 = rho2[tid]; bb2 = ba2[tid]; }
    const float beta = beta_out[0];
    float vout = 0.f, osum = 0.f;

    if (tid < 8) { s_m1[0][tid] = 0ull; s_m1[1][tid] = 0ull; }
    if (tid < 4) { s_m2[0][tid] = 0ull; s_m2[1][tid] = 0ull; }
    __syncthreads();

    for (int t = 0; t < Tv + 2; ++t) {
        const int cur = t & 1, prev = cur ^ 1;

        u64 m1[8];
        #pragma unroll
        for (int i = 0; i < 8; ++i) m1[i] = s_m1[prev][i];
        u64 anyw = 0;
        #pragma unroll
        for (int i = 0; i < 8; ++i) anyw |= m1[i];
        const bool any1 = (anyw != 0ull);

        const bool doOut = (tid < Ov) & (t >= 2);
        u64 m2[4] = {0ull, 0ull, 0ull, 0ull};
        if (doOut) {
            #pragma unroll
            for (int i = 0; i < 4; ++i) m2[i] = s_m2[prev][i];
        }

        // ---- L1 update for step t ----
        if (t < Tv) {
            const float4* xr = (const float4*)(&lds_x[t * Cv]);
            float c0 = 0.f, c1 = 0.f, c2 = 0.f, c3 = 0.f;
            #pragma unroll
            for (int i = 0; i < 10; ++i) {
                const float4 xv = xr[i];
                c0 += xv.x * w1r[i].x;
                c1 += xv.y * w1r[i].y;
                c2 += xv.z * w1r[i].z;
                c3 += xv.w * w1r[i].w;
            }
            float acc = (c0 + c1) + (c2 + c3);
            if (any1) {
                #pragma unroll
                for (int w = 0; w < 8; ++w) {
                    u64 m = m1[w];
                    while (m) {
                        const int j = (w << 6) + __builtin_ctzll(m);
                        m &= (m - 1);
                        acc += Wrec[tid * H1v + j];
                    }
                }
            }
            v1 = al1 * (v1 - spk1 * THv) + (1.f - al1) * (acc - a1p);
            const bool sp = (v1 >= THv);
            spk1 = sp ? 1.f : 0.f;
            a1p = rh1 * a1p + bb1 * spk1;
            const u64 bal = __ballot(sp);
            if (lane == 0) s_m1[cur][tid >> 6] = bal;
        }

        // ---- L2 update for step t-1 ----
        if ((tid < H2v) & (t >= 1) & (t <= Tv)) {
            float acc2 = 0.f;
            if (any1) {
                #pragma unroll
                for (int w = 0; w < 8; ++w) {
                    u64 m = m1[w];
                    while (m) {
                        const int j = (w << 6) + __builtin_ctzll(m);
                        m &= (m - 1);
                        acc2 += W2[tid * H1v + j];
                    }
                }
            }
            v2 = al2 * v2 + (1.f - al2) * (acc2 - a2);
            const bool sp2 = (v2 >= THv);
            a2 = rh2 * a2 + bb2 * (sp2 ? 1.f : 0.f);
            const u64 bal2 = __ballot(sp2);
            if (lane == 0) s_m2[cur][tid >> 6] = bal2;
        }

        // ---- Out update for step t-2 ----
        if (doOut) {
            float io = 0.f;
            if (m2[0] | m2[1] | m2[2] | m2[3]) {
                #pragma unroll
                for (int w = 0; w < 4; ++w) {
                    u64 m = m2[w];
                    while (m) {
                        const int j = (w << 6) + __builtin_ctzll(m);
                        m &= (m - 1);
                        io += Wout[tid * H2v + j];
                    }
                }
            }
            vout = beta * vout + (1.f - beta) * io;
            osum += vout;
        }

        __syncthreads();
    }

    if (tid < Ov) out[b * Ov + tid] = osum / (float)Tv;
}

extern "C" void kernel_launch(void* const* d_in, const int* in_sizes, int n_in,
                              void* d_out, int out_size, void* d_ws, size_t ws_size,
                              hipStream_t stream)
{
    const float* x       = (const float*)d_in[0];
    const float* W1      = (const float*)d_in[1];
    const float* Wrec    = (const float*)d_in[2];
    const float* W2      = (const float*)d_in[3];
    const float* Wout    = (const float*)d_in[4];
    const float* alpha1  = (const float*)d_in[5];
    const float* rho1    = (const float*)d_in[6];
    const float* ba1     = (const float*)d_in[7];
    const float* alpha2  = (const float*)d_in[8];
    const float* rho2    = (const float*)d_in[9];
    const float* ba2     = (const float*)d_in[10];
    const float* beta_o  = (const float*)d_in[11];
    float* out = (float*)d_out;

    snn_main<<<dim3(Bv), dim3(512), 0, stream>>>(
        x, W1, Wrec, W2, Wout,
        alpha1, rho1, ba1, alpha2, rho2, ba2, beta_o, out);
}

// Round 13
// 92.651 us; speedup vs baseline: 1.4199x; 1.4199x over previous
//
#include <hip/hip_runtime.h>

#define Bv 256
#define Tv 200
#define Cv 40
#define H1v 512
#define H2v 256
#define Ov 12
#define THv 1.0f
#define NT 13        // 13 tiles of 16 timesteps (padded to 208)
#define TPAD 208
#define RW 36        // u32 words per padded x row (72 f16; 40 data + 32 zero)

typedef unsigned long long u64;
typedef _Float16 half8 __attribute__((ext_vector_type(8)));
typedef float    f32x4 __attribute__((ext_vector_type(4)));
typedef _Float16 f16x2 __attribute__((ext_vector_type(2)));
typedef __fp16   g16x2 __attribute__((ext_vector_type(2)));

#if defined(__has_builtin)
#if __has_builtin(__builtin_amdgcn_fdot2)
#define HAVE_FDOT2 1
#endif
#endif

static __device__ __forceinline__ unsigned pkrtz(float a, float b) {
    union { g16x2 h; unsigned u; } cv;
    cv.h = __builtin_amdgcn_cvt_pkrtz(a, b);
    return cv.u;
}
static __device__ __forceinline__ float dot2acc(unsigned a, unsigned b, float c) {
#ifdef HAVE_FDOT2
    union { unsigned u; f16x2 h; } A, B; A.u = a; B.u = b;
    return __builtin_amdgcn_fdot2(A.h, B.h, c, false);
#else
    union { unsigned u; f16x2 h; } A, B; A.u = a; B.u = b;
    return c + (float)A.h.x * (float)B.h.x + (float)A.h.y * (float)B.h.y;
#endif
}
static __device__ __forceinline__ half8 toh8(uint4 q) {
    union { uint4 u; half8 h; } cv; cv.u = q; return cv.h;
}
static __device__ __forceinline__ float lo2f(unsigned u) {
    union { unsigned u; f16x2 h; } cv; cv.u = u; return (float)cv.h.x;
}
static __device__ __forceinline__ float hi2f(unsigned u) {
    union { unsigned u; f16x2 h; } cv; cv.u = u; return (float)cv.h.y;
}

// ---------------------------------------------------------------------------
// One block per batch element, 512 threads (8 waves).
//
// R13 = R11 (last known good: MFMA GEMM + in-register EMA scan, layout
// HW-verified by the in-kernel self-check) + ONE change: the exact 16-step
// vmax inner loop is replaced by a sound per-lane upper bound
//   v(g4+j) = al^(j+1) v_start + kk*q_j <= al*max(v_start,0) + kk*max_j q_j
// (valid for al in [0,1]; out-of-range al -> bad -> exact path). Slack
// <= (al-al^4)|v| ~ 0.03, far inside the 0.9-threshold margin.
// R12 post-mortem: bundling prefetch + staging rewrite spilled (WRITE_SIZE
// 155MB scratch, 270k bank conflicts) — reverted wholesale.
//
// Gate soundness for ANY input: err = 40*xmax*wmax*2^-8 (f16 inputs, fp32
// accum) + dmax*2^-10 (f16-packed c compose, geometric sum) + 1e-4 (fp32
// assoc). EMA convex => |v_hat-v|<=err. Fast path iff err<0.25 &&
// vmax_ub<1-err && selfcheck ok && al in range; NaN/Inf fail -> exact.
// PHASE 2 = verbatim R1 harness-verified fp32 kernel (x restaged fp32).
// ---------------------------------------------------------------------------
__global__ __launch_bounds__(512) void snn_main(
    const float* __restrict__ x,
    const float* __restrict__ W1,
    const float* __restrict__ Wrec,
    const float* __restrict__ W2,
    const float* __restrict__ Wout,
    const float* __restrict__ alpha1, const float* __restrict__ rho1, const float* __restrict__ ba1,
    const float* __restrict__ alpha2, const float* __restrict__ rho2, const float* __restrict__ ba2,
    const float* __restrict__ beta_out,
    float* __restrict__ out)
{
    // union: phase 1 = packed-f16 x [208][36 u32] (29952 B); phase 2 = fp32 x (32000 B)
    __shared__ __align__(16) unsigned char lds_u[Tv * Cv * 4];
    __shared__ __align__(16) u64 s_m1[2][8];
    __shared__ __align__(16) u64 s_m2[2][4];
    __shared__ __align__(16) u64 s_red[8];
    __shared__ float s_xmax[8], s_wmax[8], s_dmax[8];

    unsigned* lds_xh = (unsigned*)lds_u;
    float*    lds_x  = (float*)lds_u;

    const int b    = blockIdx.x;
    const int tid  = threadIdx.x;
    const int lane = tid & 63;
    const int wid  = tid >> 6;
    const int g    = lane >> 4;       // 4-row group within wave
    const int cl   = lane & 15;       // column-within-subtile

    const float* __restrict__ xg = x + (size_t)b * (Tv * Cv);

    bool bad = false;

    // --- stage x as zero-padded f16 [TPAD][RW u32]; track max|x| ---
    float xm = 0.f;
    for (int idx = tid; idx < TPAD * RW; idx += 512) {
        const int r = idx / RW, wd = idx - r * RW;
        unsigned val = 0u;
        if ((r < Tv) & (wd < 20)) {
            const float a = xg[r * Cv + 2 * wd];
            const float c = xg[r * Cv + 2 * wd + 1];
            xm = fmaxf(xm, fmaxf(fabsf(a), fabsf(c)));
            val = pkrtz(a, c);
        }
        lds_xh[idx] = val;
    }

    // --- W1 slice -> f16 B-fragments in registers (4 subtiles x 2 K-halves) ---
    uint4 bfr[4][2];
    float wm = 0.f;
    #pragma unroll
    for (int s = 0; s < 4; ++s) {
        const int h = (wid << 6) + (s << 4) + cl;
        {   // K-half 0: k = g*8 .. g*8+7 (all < 40)
            const float4 q0 = *(const float4*)(W1 + h * Cv + g * 8);
            const float4 q1 = *(const float4*)(W1 + h * Cv + g * 8 + 4);
            wm = fmaxf(wm, fmaxf(fmaxf(fabsf(q0.x), fabsf(q0.y)), fmaxf(fabsf(q0.z), fabsf(q0.w))));
            wm = fmaxf(wm, fmaxf(fmaxf(fabsf(q1.x), fabsf(q1.y)), fmaxf(fabsf(q1.z), fabsf(q1.w))));
            bfr[s][0] = make_uint4(pkrtz(q0.x, q0.y), pkrtz(q0.z, q0.w),
                                   pkrtz(q1.x, q1.y), pkrtz(q1.z, q1.w));
        }
        if (g == 0) {  // K-half 1: k = 32..39 valid only for group 0; others zero
            const float4 q2 = *(const float4*)(W1 + h * Cv + 32);
            const float4 q3 = *(const float4*)(W1 + h * Cv + 36);
            wm = fmaxf(wm, fmaxf(fmaxf(fabsf(q2.x), fabsf(q2.y)), fmaxf(fabsf(q2.z), fabsf(q2.w))));
            wm = fmaxf(wm, fmaxf(fmaxf(fabsf(q3.x), fabsf(q3.y)), fmaxf(fabsf(q3.z), fabsf(q3.w))));
            bfr[s][1] = make_uint4(pkrtz(q2.x, q2.y), pkrtz(q2.z, q2.w),
                                   pkrtz(q3.x, q3.y), pkrtz(q3.z, q3.w));
        } else {
            bfr[s][1] = make_uint4(0u, 0u, 0u, 0u);
        }
    }

    // reduce xmax / wmax to shared
    #pragma unroll
    for (int o = 32; o > 0; o >>= 1) { xm = fmaxf(xm, __shfl_xor(xm, o)); wm = fmaxf(wm, __shfl_xor(wm, o)); }
    if (lane == 0) { s_xmax[wid] = xm; s_wmax[wid] = wm; }
    __syncthreads();

    // per-lane alphas for its 4 columns (range-checked for bound soundness)
    float al[4], kk[4], al4[4], vc[4];
    #pragma unroll
    for (int s = 0; s < 4; ++s) {
        al[s] = alpha1[(wid << 6) + (s << 4) + cl];
        if (!(al[s] >= 0.f && al[s] <= 1.f)) bad = true;   // NaN also trips
        kk[s] = 1.f - al[s];
        const float a2 = al[s] * al[s];
        al4[s] = a2 * a2;
        vc[s] = 0.f;
    }

    // ================= PHASE 1: MFMA GEMM + in-register EMA scan =============
    float vmax = 0.f, dmax = 0.f;

    for (int it = 0; it < NT; ++it) {
        // A-fragments: row = it*16+cl, k-halves at word offsets g*4 and 16+g*4
        const unsigned* ap = lds_xh + (it * 16 + cl) * RW + g * 4;
        const uint4 a0 = *(const uint4*)ap;
        const uint4 a1 = *(const uint4*)(ap + 16);

        f32x4 acc[4];
        #pragma unroll
        for (int s = 0; s < 4; ++s) {
            f32x4 c = {0.f, 0.f, 0.f, 0.f};
            c = __builtin_amdgcn_mfma_f32_16x16x32_f16(toh8(a0), toh8(bfr[s][0]), c, 0, 0, 0);
            c = __builtin_amdgcn_mfma_f32_16x16x32_f16(toh8(a1), toh8(bfr[s][1]), c, 0, 0, 0);
            acc[s] = c;
        }

        // ---- one-time layout self-check: lane's subtile-0 quad vs direct dot2
        if (it == 0) {
            const int h = (wid << 6) + cl;
            unsigned wrow[20];
            #pragma unroll
            for (int m = 0; m < 10; ++m) {
                const float2 q = *(const float2*)(W1 + h * Cv + 2 * m);
                const float2 r = *(const float2*)(W1 + h * Cv + 20 + 2 * m);
                wrow[m]      = pkrtz(q.x, q.y);
                wrow[10 + m] = pkrtz(r.x, r.y);
            }
            #pragma unroll
            for (int j = 0; j < 4; ++j) {
                const int t = g * 4 + j;
                float dd = 0.f;
                #pragma unroll
                for (int m = 0; m < 20; ++m) dd = dot2acc(lds_xh[t * RW + m], wrow[m], dd);
                const float ref = acc[0][j];
                if (!(fabsf(dd - ref) <= 2e-3f + 2e-3f * fabsf(dd))) bad = true;
            }
        }

        // ---- per-subtile: Horner chain -> compose constant + q-max bound
        float cS[4], qmx[4];
        #pragma unroll
        for (int s = 0; s < 4; ++s) {
            const float d0 = acc[s][0], d1 = acc[s][1], d2 = acc[s][2], d3 = acc[s][3];
            dmax = fmaxf(dmax, fmaxf(fmaxf(fabsf(d0), fabsf(d1)), fmaxf(fabsf(d2), fabsf(d3))));
            const float q0 = d0;
            const float q1 = al[s] * q0 + d1;
            const float q2 = al[s] * q1 + d2;
            const float q3 = al[s] * q2 + d3;
            cS[s]  = kk[s] * q3;
            qmx[s] = fmaxf(fmaxf(q0, q1), fmaxf(q2, q3));
        }

        // ---- gather compose constants across the 4 row-groups (packed f16)
        const unsigned w01 = pkrtz(cS[0], cS[1]);
        const unsigned w23 = pkrtz(cS[2], cS[3]);
        unsigned cg01[4], cg23[4];
        #pragma unroll
        for (int gp = 0; gp < 4; ++gp) {
            cg01[gp] = (unsigned)__shfl((int)w01, cl + (gp << 4));
            cg23[gp] = (unsigned)__shfl((int)w23, cl + (gp << 4));
        }
        #pragma unroll
        for (int s = 0; s < 4; ++s) {
            float cgv[4];
            #pragma unroll
            for (int gp = 0; gp < 4; ++gp)
                cgv[gp] = (s == 0) ? lo2f(cg01[gp]) : (s == 1) ? hi2f(cg01[gp])
                        : (s == 2) ? lo2f(cg23[gp]) : hi2f(cg23[gp]);
            const float v0s = vc[s];
            const float v1s = al4[s] * v0s + cgv[0];
            const float v2s = al4[s] * v1s + cgv[1];
            const float v3s = al4[s] * v2s + cgv[2];
            vc[s]           = al4[s] * v3s + cgv[3];
            const float vst = (g == 0) ? v0s : (g == 1) ? v1s : (g == 2) ? v2s : v3s;
            // sound upper bound over this lane's 4 rows (al in [0,1]):
            //   v(g4+j) = al^(j+1) vst + kk q_j <= al*max(vst,0) + kk*qmax
            const float vub = al[s] * fmaxf(vst, 0.f) + kk[s] * qmx[s];
            vmax = fmaxf(vmax, vub);
        }
    }

    // block maxima + gate
    {
        float dm = dmax;
        #pragma unroll
        for (int o = 32; o > 0; o >>= 1) dm = fmaxf(dm, __shfl_xor(dm, o));
        if (lane == 0) s_dmax[wid] = dm;
    }
    __syncthreads();
    {
        float xmax = s_xmax[0], wmax = s_wmax[0], dmx = s_dmax[0];
        #pragma unroll
        for (int i = 1; i < 8; ++i) {
            xmax = fmaxf(xmax, s_xmax[i]);
            wmax = fmaxf(wmax, s_wmax[i]);
            dmx  = fmaxf(dmx,  s_dmax[i]);
        }
        const float err = 40.f * xmax * wmax * (1.f / 256.f) + dmx * (1.f / 1024.f) + 1e-4f;
        bad = bad || !((err < 0.25f) && (vmax < 1.0f - err));
    }

    {
        const u64 bal = __ballot(bad);
        if (lane == 0) s_red[wid] = bal;
        __syncthreads();
        u64 any = 0ull;
        #pragma unroll
        for (int i = 0; i < 8; ++i) any |= s_red[i];
        if (any == 0ull) {
            // Provably spike-free: every downstream signal is exactly zero.
            if (tid < Ov) out[b * Ov + tid] = 0.f;
            return;
        }
    }

    // ================= PHASE 2: exact coupled simulation (rare) ===============
    // Restage fp32 x (phase-1 f16 reads all completed before the ballot barrier).
    for (int i = tid; i < Tv * Cv; i += 512) lds_x[i] = xg[i];

    float4 w1r[10];
    {
        const float4* p = (const float4*)(W1 + tid * Cv);
        #pragma unroll
        for (int i = 0; i < 10; ++i) w1r[i] = p[i];
    }
    const float al1 = alpha1[tid];
    const float rh1 = rho1[tid], bb1 = ba1[tid];
    float v1 = 0.f, a1 = 0.f, spk1 = 0.f;
    float al2 = 0.f, rh2 = 0.f, bb2 = 0.f, v2 = 0.f, a2 = 0.f;
    if (tid < H2v) { al2 = alpha2[tid]; rh2 = rho2[tid]; bb2 = ba2[tid]; }
    const float beta = beta_out[0];
    float vout = 0.f, osum = 0.f;

    if (tid < 8) { s_m1[0][tid] = 0ull; s_m1[1][tid] = 0ull; }
    if (tid < 4) { s_m2[0][tid] = 0ull; s_m2[1][tid] = 0ull; }
    __syncthreads();

    for (int t = 0; t < Tv + 2; ++t) {
        const int cur = t & 1, prev = cur ^ 1;

        u64 m1[8];
        #pragma unroll
        for (int i = 0; i < 8; ++i) m1[i] = s_m1[prev][i];
        u64 anyw = 0;
        #pragma unroll
        for (int i = 0; i < 8; ++i) anyw |= m1[i];
        const bool any1 = (anyw != 0ull);

        const bool doOut = (tid < Ov) & (t >= 2);
        u64 m2[4] = {0ull, 0ull, 0ull, 0ull};
        if (doOut) {
            #pragma unroll
            for (int i = 0; i < 4; ++i) m2[i] = s_m2[prev][i];
        }

        // ---- L1 update for step t ----
        if (t < Tv) {
            const float4* xr = (const float4*)(&lds_x[t * Cv]);
            float c0 = 0.f, c1 = 0.f, c2 = 0.f, c3 = 0.f;
            #pragma unroll
            for (int i = 0; i < 10; ++i) {
                const float4 xv = xr[i];
                c0 += xv.x * w1r[i].x;
                c1 += xv.y * w1r[i].y;
                c2 += xv.z * w1r[i].z;
                c3 += xv.w * w1r[i].w;
            }
            float acc = (c0 + c1) + (c2 + c3);
            if (any1) {
                #pragma unroll
                for (int w = 0; w < 8; ++w) {
                    u64 m = m1[w];
                    while (m) {
                        const int j = (w << 6) + __builtin_ctzll(m);
                        m &= (m - 1);
                        acc += Wrec[tid * H1v + j];
                    }
                }
            }
            v1 = al1 * (v1 - spk1 * THv) + (1.f - al1) * (acc - a1);
            const bool sp = (v1 >= THv);
            spk1 = sp ? 1.f : 0.f;
            a1 = rh1 * a1 + bb1 * spk1;
            const u64 bal = __ballot(sp);
            if (lane == 0) s_m1[cur][tid >> 6] = bal;
        }

        // ---- L2 update for step t-1 ----
        if ((tid < H2v) & (t >= 1) & (t <= Tv)) {
            float acc2 = 0.f;
            if (any1) {
                #pragma unroll
                for (int w = 0; w < 8; ++w) {
                    u64 m = m1[w];
                    while (m) {
                        const int j = (w << 6) + __builtin_ctzll(m);
                        m &= (m - 1);
                        acc2 += W2[tid * H1v + j];
                    }
                }
            }
            v2 = al2 * v2 + (1.f - al2) * (acc2 - a2);
            const bool sp2 = (v2 >= THv);
            a2 = rh2 * a2 + bb2 * (sp2 ? 1.f : 0.f);
            const u64 bal2 = __ballot(sp2);
            if (lane == 0) s_m2[cur][tid >> 6] = bal2;
        }

        // ---- Out update for step t-2 ----
        if (doOut) {
            float io = 0.f;
            if (m2[0] | m2[1] | m2[2] | m2[3]) {
                #pragma unroll
                for (int w = 0; w < 4; ++w) {
                    u64 m = m2[w];
                    while (m) {
                        const int j = (w << 6) + __builtin_ctzll(m);
                        m &= (m - 1);
                        io += Wout[tid * H2v + j];
                    }
                }
            }
            vout = beta * vout + (1.f - beta) * io;
            osum += vout;
        }

        __syncthreads();
    }

    if (tid < Ov) out[b * Ov + tid] = osum / (float)Tv;
}

extern "C" void kernel_launch(void* const* d_in, const int* in_sizes, int n_in,
                              void* d_out, int out_size, void* d_ws, size_t ws_size,
                              hipStream_t stream)
{
    const float* x       = (const float*)d_in[0];
    const float* W1      = (const float*)d_in[1];
    const float* Wrec    = (const float*)d_in[2];
    const float* W2      = (const float*)d_in[3];
    const float* Wout    = (const float*)d_in[4];
    const float* alpha1  = (const float*)d_in[5];
    const float* rho1    = (const float*)d_in[6];
    const float* ba1     = (const float*)d_in[7];
    const float* alpha2  = (const float*)d_in[8];
    const float* rho2    = (const float*)d_in[9];
    const float* ba2     = (const float*)d_in[10];
    const float* beta_o  = (const float*)d_in[11];
    float* out = (float*)d_out;

    snn_main<<<dim3(Bv), dim3(512), 0, stream>>>(
        x, W1, Wrec, W2, Wout,
        alpha1, rho1, ba1, alpha2, rho2, ba2, beta_o, out);
}

// Round 14
// 87.153 us; speedup vs baseline: 1.5095x; 1.0631x over previous
//
#include <hip/hip_runtime.h>

#define Bv 256
#define Tv 200
#define Cv 40
#define H1v 512
#define H2v 256
#define Ov 12
#define THv 1.0f
#define NT 13        // 13 tiles of 16 timesteps (padded to 208)
#define TPAD 208
#define RW 36        // u32 words per padded x row (72 f16; 40 data + 32 zero)

typedef unsigned long long u64;
typedef _Float16 half8 __attribute__((ext_vector_type(8)));
typedef float    f32x4 __attribute__((ext_vector_type(4)));
typedef _Float16 f16x2 __attribute__((ext_vector_type(2)));
typedef __fp16   g16x2 __attribute__((ext_vector_type(2)));

#if defined(__has_builtin)
#if __has_builtin(__builtin_amdgcn_fdot2)
#define HAVE_FDOT2 1
#endif
#endif

static __device__ __forceinline__ unsigned pkrtz(float a, float b) {
    union { g16x2 h; unsigned u; } cv;
    cv.h = __builtin_amdgcn_cvt_pkrtz(a, b);
    return cv.u;
}
static __device__ __forceinline__ float dot2acc(unsigned a, unsigned b, float c) {
#ifdef HAVE_FDOT2
    union { unsigned u; f16x2 h; } A, B; A.u = a; B.u = b;
    return __builtin_amdgcn_fdot2(A.h, B.h, c, false);
#else
    union { unsigned u; f16x2 h; } A, B; A.u = a; B.u = b;
    return c + (float)A.h.x * (float)B.h.x + (float)A.h.y * (float)B.h.y;
#endif
}
static __device__ __forceinline__ half8 toh8(uint4 q) {
    union { uint4 u; half8 h; } cv; cv.u = q; return cv.h;
}
static __device__ __forceinline__ float lo2f(unsigned u) {
    union { unsigned u; f16x2 h; } cv; cv.u = u; return (float)cv.h.x;
}
static __device__ __forceinline__ float hi2f(unsigned u) {
    union { unsigned u; f16x2 h; } cv; cv.u = u; return (float)cv.h.y;
}

// ---------------------------------------------------------------------------
// One block per batch element, 512 threads (8 waves).
//
// R14 = R13 (MFMA GEMM + in-register EMA scan, layout HW-verified by the
// in-kernel self-check) + latency fixes from the R13 null-result diagnosis
// (phase 1 is latency-bound: static issue ~3us vs measured ~26us):
//  (a) staging split into issue-then-process: 8 unconditional batched
//      float2 loads -> regs (one latency shadow instead of ~15 serialized
//      iterations), then pure-VALU fmax/pkrtz/ds_write; pad-zero loop
//      separate;
//  (b) dmax tracking deleted; bounded analytically by 40*xmax*wmax*1.01
//      (40 f16-rounded terms), removing ~35 instr/tile + one barrier.
//
// Gate soundness for ANY input: err = 40*xmax*wmax/256 (f16 inputs, fp32
// accum) + 40*xmax*wmax*1.01/1024 (f16-packed c compose, geometric sum)
// + 1e-4 (fp32 assoc). EMA convex => |v_hat-v|<=err. Fast path iff
// err<0.25 && vmax_ub<1-err && selfcheck ok && al in [0,1]; NaN/Inf fail
// -> exact. PHASE 2 = verbatim R1 harness-verified fp32 kernel.
// ---------------------------------------------------------------------------
__global__ __launch_bounds__(512) void snn_main(
    const float* __restrict__ x,
    const float* __restrict__ W1,
    const float* __restrict__ Wrec,
    const float* __restrict__ W2,
    const float* __restrict__ Wout,
    const float* __restrict__ alpha1, const float* __restrict__ rho1, const float* __restrict__ ba1,
    const float* __restrict__ alpha2, const float* __restrict__ rho2, const float* __restrict__ ba2,
    const float* __restrict__ beta_out,
    float* __restrict__ out)
{
    // union: phase 1 = packed-f16 x [208][36 u32] (29952 B); phase 2 = fp32 x (32000 B)
    __shared__ __align__(16) unsigned char lds_u[Tv * Cv * 4];
    __shared__ __align__(16) u64 s_m1[2][8];
    __shared__ __align__(16) u64 s_m2[2][4];
    __shared__ __align__(16) u64 s_red[8];
    __shared__ float s_xmax[8], s_wmax[8];

    unsigned* lds_xh = (unsigned*)lds_u;
    float*    lds_x  = (float*)lds_u;

    const int b    = blockIdx.x;
    const int tid  = threadIdx.x;
    const int lane = tid & 63;
    const int wid  = tid >> 6;
    const int g    = lane >> 4;       // 4-row group within wave
    const int cl   = lane & 15;       // column-within-subtile

    const float* __restrict__ xg = x + (size_t)b * (Tv * Cv);

    bool bad = false;

    // --- pad-zero loop: rows 0..199 words 20..35 (3200) + rows 200..207 (288) ---
    for (int k = 0; k < 7; ++k) {
        const int p = tid + (k << 9);
        if (p < 3200)       lds_xh[(p >> 4) * RW + 20 + (p & 15)] = 0u;
        else if (p < 3488)  lds_xh[7200 + (p - 3200)] = 0u;
    }

    // --- data staging: 4000 u32 words; 8 batched float2 loads then process ---
    float xm = 0.f;
    {
        float2 xv[8];
        #pragma unroll
        for (int k = 0; k < 8; ++k) {
            const int p  = tid + (k << 9);
            const int pc = (p < 4000) ? p : 3999;        // clamp: load always legal
            const int r  = pc / 20, wd = pc - r * 20;
            xv[k] = *(const float2*)(xg + r * Cv + 2 * wd);
        }
        #pragma unroll
        for (int k = 0; k < 8; ++k) {
            const int p = tid + (k << 9);
            if (p < 4000) {
                const int r = p / 20, wd = p - r * 20;
                xm = fmaxf(xm, fmaxf(fabsf(xv[k].x), fabsf(xv[k].y)));
                lds_xh[r * RW + wd] = pkrtz(xv[k].x, xv[k].y);
            }
        }
    }

    // --- W1 slice -> f16 B-fragments in registers (4 subtiles x 2 K-halves) ---
    uint4 bfr[4][2];
    float wm = 0.f;
    #pragma unroll
    for (int s = 0; s < 4; ++s) {
        const int h = (wid << 6) + (s << 4) + cl;
        {   // K-half 0: k = g*8 .. g*8+7 (all < 40)
            const float4 q0 = *(const float4*)(W1 + h * Cv + g * 8);
            const float4 q1 = *(const float4*)(W1 + h * Cv + g * 8 + 4);
            wm = fmaxf(wm, fmaxf(fmaxf(fabsf(q0.x), fabsf(q0.y)), fmaxf(fabsf(q0.z), fabsf(q0.w))));
            wm = fmaxf(wm, fmaxf(fmaxf(fabsf(q1.x), fabsf(q1.y)), fmaxf(fabsf(q1.z), fabsf(q1.w))));
            bfr[s][0] = make_uint4(pkrtz(q0.x, q0.y), pkrtz(q0.z, q0.w),
                                   pkrtz(q1.x, q1.y), pkrtz(q1.z, q1.w));
        }
        if (g == 0) {  // K-half 1: k = 32..39 valid only for group 0; others zero
            const float4 q2 = *(const float4*)(W1 + h * Cv + 32);
            const float4 q3 = *(const float4*)(W1 + h * Cv + 36);
            wm = fmaxf(wm, fmaxf(fmaxf(fabsf(q2.x), fabsf(q2.y)), fmaxf(fabsf(q2.z), fabsf(q2.w))));
            wm = fmaxf(wm, fmaxf(fmaxf(fabsf(q3.x), fabsf(q3.y)), fmaxf(fabsf(q3.z), fabsf(q3.w))));
            bfr[s][1] = make_uint4(pkrtz(q2.x, q2.y), pkrtz(q2.z, q2.w),
                                   pkrtz(q3.x, q3.y), pkrtz(q3.z, q3.w));
        } else {
            bfr[s][1] = make_uint4(0u, 0u, 0u, 0u);
        }
    }

    // reduce xmax / wmax to shared
    #pragma unroll
    for (int o = 32; o > 0; o >>= 1) { xm = fmaxf(xm, __shfl_xor(xm, o)); wm = fmaxf(wm, __shfl_xor(wm, o)); }
    if (lane == 0) { s_xmax[wid] = xm; s_wmax[wid] = wm; }
    __syncthreads();

    // per-lane alphas for its 4 columns (range-checked for bound soundness)
    float al[4], kk[4], al4[4], vc[4];
    #pragma unroll
    for (int s = 0; s < 4; ++s) {
        al[s] = alpha1[(wid << 6) + (s << 4) + cl];
        if (!(al[s] >= 0.f && al[s] <= 1.f)) bad = true;   // NaN also trips
        kk[s] = 1.f - al[s];
        const float a2 = al[s] * al[s];
        al4[s] = a2 * a2;
        vc[s] = 0.f;
    }

    // ================= PHASE 1: MFMA GEMM + in-register EMA scan =============
    float vmax = 0.f;

    for (int it = 0; it < NT; ++it) {
        // A-fragments: row = it*16+cl, k-halves at word offsets g*4 and 16+g*4
        const unsigned* ap = lds_xh + (it * 16 + cl) * RW + g * 4;
        const uint4 a0 = *(const uint4*)ap;
        const uint4 a1 = *(const uint4*)(ap + 16);

        f32x4 acc[4];
        #pragma unroll
        for (int s = 0; s < 4; ++s) {
            f32x4 c = {0.f, 0.f, 0.f, 0.f};
            c = __builtin_amdgcn_mfma_f32_16x16x32_f16(toh8(a0), toh8(bfr[s][0]), c, 0, 0, 0);
            c = __builtin_amdgcn_mfma_f32_16x16x32_f16(toh8(a1), toh8(bfr[s][1]), c, 0, 0, 0);
            acc[s] = c;
        }

        // ---- one-time layout self-check: lane's subtile-0 quad vs direct dot2
        if (it == 0) {
            const int h = (wid << 6) + cl;
            unsigned wrow[20];
            #pragma unroll
            for (int m = 0; m < 10; ++m) {
                const float2 q = *(const float2*)(W1 + h * Cv + 2 * m);
                const float2 r = *(const float2*)(W1 + h * Cv + 20 + 2 * m);
                wrow[m]      = pkrtz(q.x, q.y);
                wrow[10 + m] = pkrtz(r.x, r.y);
            }
            #pragma unroll
            for (int j = 0; j < 4; ++j) {
                const int t = g * 4 + j;
                float dd = 0.f;
                #pragma unroll
                for (int m = 0; m < 20; ++m) dd = dot2acc(lds_xh[t * RW + m], wrow[m], dd);
                const float ref = acc[0][j];
                if (!(fabsf(dd - ref) <= 2e-3f + 2e-3f * fabsf(dd))) bad = true;
            }
        }

        // ---- per-subtile: Horner chain -> compose constant + q-max bound
        float cS[4], qmx[4];
        #pragma unroll
        for (int s = 0; s < 4; ++s) {
            const float d0 = acc[s][0], d1 = acc[s][1], d2 = acc[s][2], d3 = acc[s][3];
            const float q0 = d0;
            const float q1 = al[s] * q0 + d1;
            const float q2 = al[s] * q1 + d2;
            const float q3 = al[s] * q2 + d3;
            cS[s]  = kk[s] * q3;
            qmx[s] = fmaxf(fmaxf(q0, q1), fmaxf(q2, q3));
        }

        // ---- gather compose constants across the 4 row-groups (packed f16)
        const unsigned w01 = pkrtz(cS[0], cS[1]);
        const unsigned w23 = pkrtz(cS[2], cS[3]);
        unsigned cg01[4], cg23[4];
        #pragma unroll
        for (int gp = 0; gp < 4; ++gp) {
            cg01[gp] = (unsigned)__shfl((int)w01, cl + (gp << 4));
            cg23[gp] = (unsigned)__shfl((int)w23, cl + (gp << 4));
        }
        #pragma unroll
        for (int s = 0; s < 4; ++s) {
            float cgv[4];
            #pragma unroll
            for (int gp = 0; gp < 4; ++gp)
                cgv[gp] = (s == 0) ? lo2f(cg01[gp]) : (s == 1) ? hi2f(cg01[gp])
                        : (s == 2) ? lo2f(cg23[gp]) : hi2f(cg23[gp]);
            const float v0s = vc[s];
            const float v1s = al4[s] * v0s + cgv[0];
            const float v2s = al4[s] * v1s + cgv[1];
            const float v3s = al4[s] * v2s + cgv[2];
            vc[s]           = al4[s] * v3s + cgv[3];
            const float vst = (g == 0) ? v0s : (g == 1) ? v1s : (g == 2) ? v2s : v3s;
            // sound upper bound over this lane's 4 rows (al in [0,1]):
            //   v(g4+j) = al^(j+1) vst + kk q_j <= al*max(vst,0) + kk*qmax
            const float vub = al[s] * fmaxf(vst, 0.f) + kk[s] * qmx[s];
            vmax = fmaxf(vmax, vub);
        }
    }

    // gate (dmax bounded analytically: |d| <= 40*xmax*wmax*1.01)
    {
        float xmax = s_xmax[0], wmax = s_wmax[0];
        #pragma unroll
        for (int i = 1; i < 8; ++i) {
            xmax = fmaxf(xmax, s_xmax[i]);
            wmax = fmaxf(wmax, s_wmax[i]);
        }
        const float dwb = 40.f * xmax * wmax;
        const float err = dwb * (1.f / 256.f) + dwb * 1.01f * (1.f / 1024.f) + 1e-4f;
        bad = bad || !((err < 0.25f) && (vmax < 1.0f - err));
    }

    {
        const u64 bal = __ballot(bad);
        if (lane == 0) s_red[wid] = bal;
        __syncthreads();
        u64 any = 0ull;
        #pragma unroll
        for (int i = 0; i < 8; ++i) any |= s_red[i];
        if (any == 0ull) {
            // Provably spike-free: every downstream signal is exactly zero.
            if (tid < Ov) out[b * Ov + tid] = 0.f;
            return;
        }
    }

    // ================= PHASE 2: exact coupled simulation (rare) ===============
    // Restage fp32 x (phase-1 f16 reads all completed before the ballot barrier).
    for (int i = tid; i < Tv * Cv; i += 512) lds_x[i] = xg[i];

    float4 w1r[10];
    {
        const float4* p = (const float4*)(W1 + tid * Cv);
        #pragma unroll
        for (int i = 0; i < 10; ++i) w1r[i] = p[i];
    }
    const float al1 = alpha1[tid];
    const float rh1 = rho1[tid], bb1 = ba1[tid];
    float v1 = 0.f, a1 = 0.f, spk1 = 0.f;
    float al2 = 0.f, rh2 = 0.f, bb2 = 0.f, v2 = 0.f, a2 = 0.f;
    if (tid < H2v) { al2 = alpha2[tid]; rh2 = rho2[tid]; bb2 = ba2[tid]; }
    const float beta = beta_out[0];
    float vout = 0.f, osum = 0.f;

    if (tid < 8) { s_m1[0][tid] = 0ull; s_m1[1][tid] = 0ull; }
    if (tid < 4) { s_m2[0][tid] = 0ull; s_m2[1][tid] = 0ull; }
    __syncthreads();

    for (int t = 0; t < Tv + 2; ++t) {
        const int cur = t & 1, prev = cur ^ 1;

        u64 m1[8];
        #pragma unroll
        for (int i = 0; i < 8; ++i) m1[i] = s_m1[prev][i];
        u64 anyw = 0;
        #pragma unroll
        for (int i = 0; i < 8; ++i) anyw |= m1[i];
        const bool any1 = (anyw != 0ull);

        const bool doOut = (tid < Ov) & (t >= 2);
        u64 m2[4] = {0ull, 0ull, 0ull, 0ull};
        if (doOut) {
            #pragma unroll
            for (int i = 0; i < 4; ++i) m2[i] = s_m2[prev][i];
        }

        // ---- L1 update for step t ----
        if (t < Tv) {
            const float4* xr = (const float4*)(&lds_x[t * Cv]);
            float c0 = 0.f, c1 = 0.f, c2 = 0.f, c3 = 0.f;
            #pragma unroll
            for (int i = 0; i < 10; ++i) {
                const float4 xv = xr[i];
                c0 += xv.x * w1r[i].x;
                c1 += xv.y * w1r[i].y;
                c2 += xv.z * w1r[i].z;
                c3 += xv.w * w1r[i].w;
            }
            float acc = (c0 + c1) + (c2 + c3);
            if (any1) {
                #pragma unroll
                for (int w = 0; w < 8; ++w) {
                    u64 m = m1[w];
                    while (m) {
                        const int j = (w << 6) + __builtin_ctzll(m);
                        m &= (m - 1);
                        acc += Wrec[tid * H1v + j];
                    }
                }
            }
            v1 = al1 * (v1 - spk1 * THv) + (1.f - al1) * (acc - a1);
            const bool sp = (v1 >= THv);
            spk1 = sp ? 1.f : 0.f;
            a1 = rh1 * a1 + bb1 * spk1;
            const u64 bal = __ballot(sp);
            if (lane == 0) s_m1[cur][tid >> 6] = bal;
        }

        // ---- L2 update for step t-1 ----
        if ((tid < H2v) & (t >= 1) & (t <= Tv)) {
            float acc2 = 0.f;
            if (any1) {
                #pragma unroll
                for (int w = 0; w < 8; ++w) {
                    u64 m = m1[w];
                    while (m) {
                        const int j = (w << 6) + __builtin_ctzll(m);
                        m &= (m - 1);
                        acc2 += W2[tid * H1v + j];
                    }
                }
            }
            v2 = al2 * v2 + (1.f - al2) * (acc2 - a2);
            const bool sp2 = (v2 >= THv);
            a2 = rh2 * a2 + bb2 * (sp2 ? 1.f : 0.f);
            const u64 bal2 = __ballot(sp2);
            if (lane == 0) s_m2[cur][tid >> 6] = bal2;
        }

        // ---- Out update for step t-2 ----
        if (doOut) {
            float io = 0.f;
            if (m2[0] | m2[1] | m2[2] | m2[3]) {
                #pragma unroll
                for (int w = 0; w < 4; ++w) {
                    u64 m = m2[w];
                    while (m) {
                        const int j = (w << 6) + __builtin_ctzll(m);
                        m &= (m - 1);
                        io += Wout[tid * H2v + j];
                    }
                }
            }
            vout = beta * vout + (1.f - beta) * io;
            osum += vout;
        }

        __syncthreads();
    }

    if (tid < Ov) out[b * Ov + tid] = osum / (float)Tv;
}

extern "C" void kernel_launch(void* const* d_in, const int* in_sizes, int n_in,
                              void* d_out, int out_size, void* d_ws, size_t ws_size,
                              hipStream_t stream)
{
    const float* x       = (const float*)d_in[0];
    const float* W1      = (const float*)d_in[1];
    const float* Wrec    = (const float*)d_in[2];
    const float* W2      = (const float*)d_in[3];
    const float* Wout    = (const float*)d_in[4];
    const float* alpha1  = (const float*)d_in[5];
    const float* rho1    = (const float*)d_in[6];
    const float* ba1     = (const float*)d_in[7];
    const float* alpha2  = (const float*)d_in[8];
    const float* rho2    = (const float*)d_in[9];
    const float* ba2     = (const float*)d_in[10];
    const float* beta_o  = (const float*)d_in[11];
    float* out = (float*)d_out;

    snn_main<<<dim3(Bv), dim3(512), 0, stream>>>(
        x, W1, Wrec, W2, Wout,
        alpha1, rho1, ba1, alpha2, rho2, ba2, beta_o, out);
}